// Round 9
// baseline (1067.679 us; speedup 1.0000x reference)
//
#include <hip/hip_runtime.h>

// SSGC: h = alpha*x0 + (1-alpha)/K * sum_{k=1..K} (D^-1/2 A_hat D^-1/2)^k x0 ; out = h W^T + b
// N=50000, E=1.6M, D=128, K=16, alpha=0.05.
// R16 = R15 with compile fixes: __builtin_nontemporal_* rejects HIP_vector_type
//      (int4/int2) -> use clang ext_vector_type ints for 16B nt accesses and pack
//      the 8B csr record as long long.
//      R15 theory under test:
//      (1) deg/scatter nt streams. deg's WRITE_SIZE=56MB >> rank(6.4MB) revealed
//      dirty-line write-through churn: the dst/rank streams evict the hot degR
//      atomic lines; 56MB at ~0.9TB/s ~ the whole 67us kernel. nt hints keep the
//      1.6MB degR L2-resident. Predicted: deg 67 -> 25-40us, WRITE_SIZE -> ~12MB.
//      (2) agg: replace the 2 ds_bpermute/edge broadcast with per-wave LDS stage
//      (1 ds_write_b64/lane/batch) + 1 uniform ds_read_b64/edge. Wave-per-node
//      structure unchanged (R10-R13 proved restructures lose).
//      Keeps: R14 32-bit gather offsets, nt CSR/yb/h, replicated histogram,
//      3-dispatch scan, bf16 rows, h RMW every 2 hops, f32 64x64 GEMM.

#define N_NODES 50000
#define N_EDGES 1600000
#define D 128
#define K_HOPS 16
#define ALPHA 0.05f
#define HCOEF ((1.0f - ALPHA) / (float)K_HOPS)
#define NREP 8
#define N_SBLK ((N_NODES + 255) / 256)   // 196 scan blocks

// deg: 8 edges/thread -> replica of edge i is ((i >> 11) & 7) (2048 edges per block).
#define DEG_IPT 8
#define REP_OF(i) (((i) >> 11) & (NREP - 1))

typedef int  iv4 __attribute__((ext_vector_type(4)));   // nt-compatible 16B int vector

__device__ __forceinline__ unsigned int f2bf(float f) {
    unsigned int u = __float_as_uint(f);
    return (u + 0x7FFFu + ((u >> 16) & 1u)) >> 16;   // RNE
}
__device__ __forceinline__ unsigned int pack_bf2(float x, float y) {
    return f2bf(x) | (f2bf(y) << 16);
}
__device__ __forceinline__ float bf_lo(unsigned int w) { return __uint_as_float(w << 16); }
__device__ __forceinline__ float bf_hi(unsigned int w) { return __uint_as_float(w & 0xFFFF0000u); }

// Replicated in-degree histogram, 8 edges per thread (two nt 16B loads).
// All streaming traffic nt so the hot degR lines stay resident in L2.
__global__ void deg_kernel(const int* __restrict__ dst, int* __restrict__ degR,
                           int* __restrict__ rank, int e) {
    int gid = blockIdx.x * 256 + threadIdx.x;
    int i0 = gid * DEG_IPT;
    if (i0 >= e) return;
    int rep = REP_OF(i0);                    // all 8 edges share one replica
    int* base = degR + rep * N_NODES;
    iv4 d0 = __builtin_nontemporal_load((const iv4*)&dst[i0]);
    iv4 d1 = __builtin_nontemporal_load((const iv4*)&dst[i0 + 4]);
    iv4 r0, r1;
    r0.x = atomicAdd(&base[d0.x], 1);
    r0.y = atomicAdd(&base[d0.y], 1);
    r0.z = atomicAdd(&base[d0.z], 1);
    r0.w = atomicAdd(&base[d0.w], 1);
    r1.x = atomicAdd(&base[d1.x], 1);
    r1.y = atomicAdd(&base[d1.y], 1);
    r1.z = atomicAdd(&base[d1.z], 1);
    r1.w = atomicAdd(&base[d1.w], 1);
    __builtin_nontemporal_store(r0, (iv4*)&rank[i0]);
    __builtin_nontemporal_store(r1, (iv4*)&rank[i0 + 4]);
}

// Fold replicas: degR[r][i] becomes the exclusive prefix over replicas (pref),
// deg[i] = total. Also computes dinv/selfw.
__global__ void combine_kernel(int* __restrict__ degR, int* __restrict__ deg,
                               float* __restrict__ dinv, float* __restrict__ selfw, int n) {
    int i = blockIdx.x * 256 + threadIdx.x;
    if (i < n) {
        int run = 0;
        #pragma unroll
        for (int r = 0; r < NREP; ++r) {
            int v = degR[r * N_NODES + i];
            degR[r * N_NODES + i] = run;   // in-place: degR becomes pref
            run += v;
        }
        deg[i] = run;
        float di = rsqrtf((float)(run + 1));
        dinv[i] = di;
        selfw[i] = di * di;
    }
}

// 256-thread block exclusive scan (shfl wave scans + 4-wave LDS combine).
__device__ __forceinline__ int block_scan_excl(int v) {
    __shared__ int ws[4];
    int tid = threadIdx.x, lane = tid & 63, wid = tid >> 6;
    int s = v;
    #pragma unroll
    for (int off = 1; off < 64; off <<= 1) {
        int t = __shfl_up(s, off, 64);
        if (lane >= off) s += t;
    }
    if (lane == 63) ws[wid] = s;
    __syncthreads();
    int woff = 0;
    #pragma unroll
    for (int w = 0; w < 3; ++w)
        if (w < wid) woff += ws[w];
    return woff + s - v;
}

__global__ void scan_part(const int* __restrict__ deg, int* __restrict__ part, int n) {
    int i = blockIdx.x * 256 + threadIdx.x;
    int v = (i < n) ? deg[i] : 0;
    #pragma unroll
    for (int off = 1; off < 64; off <<= 1) v += __shfl_xor(v, off, 64);
    __shared__ int ws[4];
    if ((threadIdx.x & 63) == 0) ws[threadIdx.x >> 6] = v;
    __syncthreads();
    if (threadIdx.x == 0) part[blockIdx.x] = ws[0] + ws[1] + ws[2] + ws[3];
}

__global__ void scan_mid(int* __restrict__ part, int nb) {
    int tid = threadIdx.x;
    int v = (tid < nb) ? part[tid] : 0;
    int e = block_scan_excl(v);
    if (tid < nb) part[tid] = e;
}

__global__ void scan_fin(const int* __restrict__ deg, const int* __restrict__ part,
                         int* __restrict__ row_start, int n) {
    int i = blockIdx.x * 256 + threadIdx.x;
    int v = (i < n) ? deg[i] : 0;
    int e = block_scan_excl(v) + part[blockIdx.x];
    if (i < n) row_start[i] = e;
    if (i == n - 1) row_start[n] = e + v;
}

// One 8B scattered store per edge: record = (src, bitcast(norm weight)) packed
// into a long long for the nt store. 4 edges/thread for MLP.
__global__ void scatter_kernel(const int* __restrict__ src, const int* __restrict__ dst,
                               const int* __restrict__ rank, const int* __restrict__ row_start,
                               const int* __restrict__ pref, long long* __restrict__ csr,
                               const float* __restrict__ dinv, int e) {
    int gid = blockIdx.x * 256 + threadIdx.x;
    int i0 = gid * 4;
    if (i0 >= e) return;
    iv4 dv = __builtin_nontemporal_load((const iv4*)&dst[i0]);
    iv4 sv = __builtin_nontemporal_load((const iv4*)&src[i0]);
    iv4 rv = __builtin_nontemporal_load((const iv4*)&rank[i0]);
    int d[4] = {dv.x, dv.y, dv.z, dv.w};
    int s[4] = {sv.x, sv.y, sv.z, sv.w};
    int r[4] = {rv.x, rv.y, rv.z, rv.w};
    int pos[4];
    float w[4];
    #pragma unroll
    for (int q = 0; q < 4; ++q) {
        int rep = REP_OF(i0 + q);
        pos[q] = row_start[d[q]] + pref[rep * N_NODES + d[q]] + r[q];
        w[q] = dinv[d[q]] * dinv[s[q]];
    }
    #pragma unroll
    for (int q = 0; q < 4; ++q) {
        long long rec = (long long)(unsigned int)s[q]
                      | ((long long)__float_as_int(w[q]) << 32);
        __builtin_nontemporal_store(rec, &csr[pos[q]]);
    }
}

// x0 -> packed bf16 x; h = alpha * x0 (exact f32).
__global__ void init_kernel(const float2* __restrict__ x0, unsigned int* __restrict__ xb,
                            float2* __restrict__ h, int n2) {
    int i = blockIdx.x * blockDim.x + threadIdx.x;
    if (i < n2) {
        float2 v = x0[i];
        xb[i] = pack_bf2(v.x, v.y);
        h[i] = make_float2(ALPHA * v.x, ALPHA * v.y);
    }
}

// Records broadcast from per-wave LDS: ONE uniform-address ds_read_b64 per edge
// delivers (src, weight) to all lanes (replaces 2 ds_bpermute). 32-bit gather
// offsets (xb spans 12.8MB).
#define GATHER_BLOCK(W)                                                         \
    {                                                                           \
        unsigned int g[W];                                                      \
        float wv[W];                                                            \
        _Pragma("unroll") for (int q = 0; q < W; ++q) {                         \
            int2 rq = srec[wid][j + q];                                         \
            wv[q] = __int_as_float(rq.y);                                       \
            g[q] = xb[(unsigned int)rq.x * 64u + (unsigned int)lane];           \
        }                                                                       \
        _Pragma("unroll") for (int q = 0; q < W; ++q) {                         \
            accx += wv[q] * bf_lo(g[q]);                                        \
            accy += wv[q] * bf_hi(g[q]);                                        \
        }                                                                       \
        j += W;                                                                 \
    }

// One wave (64 lanes) per node; lane owns features [2*lane, 2*lane+1] (one packed
// dword). Edge records: 64-at-a-time coalesced nt load -> per-wave LDS region
// (no barrier: wave-private, lgkmcnt-ordered) -> uniform ds_read_b64 broadcast.
// Stepped unroll 16/8/4. yb nt-stored; h RMW (every 2nd hop) nt both ways.
__global__ __launch_bounds__(256) void agg_kernel(
    const unsigned int* __restrict__ xb, unsigned int* __restrict__ yb,
    float2* __restrict__ h2, const float* __restrict__ selfw,
    const int* __restrict__ row_start, const long long* __restrict__ csr, int update_h) {
    __shared__ int2 srec[4][64];               // 2KB: per-wave record stage
    int wid = threadIdx.x >> 6;
    int lane = threadIdx.x & 63;
    int node = blockIdx.x * 4 + wid;
    if (node >= N_NODES) return;

    int r0 = row_start[node];
    int r1 = row_start[node + 1];
    int deg = r1 - r0;
    unsigned int o = (unsigned int)node * 64u + (unsigned int)lane;

    unsigned int vw = xb[o];
    float sw = selfw[node];
    float accx = sw * bf_lo(vw), accy = sw * bf_hi(vw);

    for (int base = 0; base < deg; base += 64) {
        int cnt = deg - base;
        if (cnt > 64) cnt = 64;
        int idx = r0 + base + lane;
        if (idx >= r1) idx = r1 - 1;           // clamped slots never read (j < cnt)
        long long rr = __builtin_nontemporal_load(&csr[idx]);
        srec[wid][lane] = make_int2((int)rr, (int)(rr >> 32));

        int j = 0;
        while (j + 16 <= cnt) GATHER_BLOCK(16);
        if (j + 8 <= cnt) GATHER_BLOCK(8);
        if (j + 4 <= cnt) GATHER_BLOCK(4);
        for (; j < cnt; ++j) {
            int2 rq = srec[wid][j];
            float w = __int_as_float(rq.y);
            unsigned int gw = xb[(unsigned int)rq.x * 64u + (unsigned int)lane];
            accx += w * bf_lo(gw);
            accy += w * bf_hi(gw);
        }
    }

    __builtin_nontemporal_store(pack_bf2(accx, accy), &yb[o]);   // bf16 next-hop state
    if (update_h) {
        union { long long ll; float2 f; } hu;
        hu.ll = __builtin_nontemporal_load((const long long*)&h2[o]);
        hu.f.x += HCOEF * (bf_lo(vw) + accx);  // x_k (rounded) + x_{k+1} (pre-round)
        hu.f.y += HCOEF * (bf_hi(vw) + accy);
        __builtin_nontemporal_store(hu.ll, (long long*)&h2[o]);
    }
}

// out[r][c] = sum_k h[r][k]*W[c][k] + bias[c]. h and out are DIFFERENT buffers.
// Block: 64 rows x 64 cols, 256 threads, 4x4 acc/thread. k-major LDS tiles.
__global__ __launch_bounds__(256) void gemm_kernel(
    const float* __restrict__ h, const float* __restrict__ w,
    const float* __restrict__ bias, float* __restrict__ out) {
    __shared__ float sAT[128][64];   // [k][row]
    __shared__ float sBT[128][64];   // [k][col]
    int tid = threadIdx.x;
    int row0 = blockIdx.x * 64;
    int col0 = blockIdx.y * 64;

    for (int idx = tid; idx < 64 * 32; idx += 256) {
        int r = idx & 63, kq = idx >> 6;
        float4 v;
        if (row0 + r < N_NODES)
            v = *(const float4*)&h[(size_t)(row0 + r) * D + kq * 4];
        else
            v = make_float4(0.f, 0.f, 0.f, 0.f);
        sAT[kq * 4 + 0][r] = v.x;
        sAT[kq * 4 + 1][r] = v.y;
        sAT[kq * 4 + 2][r] = v.z;
        sAT[kq * 4 + 3][r] = v.w;
    }
    for (int idx = tid; idx < 64 * 32; idx += 256) {
        int c = idx & 63, kq = idx >> 6;
        float4 v = *(const float4*)&w[(size_t)(col0 + c) * D + kq * 4];
        sBT[kq * 4 + 0][c] = v.x;
        sBT[kq * 4 + 1][c] = v.y;
        sBT[kq * 4 + 2][c] = v.z;
        sBT[kq * 4 + 3][c] = v.w;
    }
    __syncthreads();

    int cg = tid & 15;    // cols cg*4..+4
    int rg = tid >> 4;    // rows rg*4..+4
    float acc[4][4] = {};
    #pragma unroll 2
    for (int k = 0; k < 128; ++k) {
        float4 a = *(const float4*)&sAT[k][rg * 4];
        float4 b = *(const float4*)&sBT[k][cg * 4];
        acc[0][0] += a.x * b.x; acc[0][1] += a.x * b.y; acc[0][2] += a.x * b.z; acc[0][3] += a.x * b.w;
        acc[1][0] += a.y * b.x; acc[1][1] += a.y * b.y; acc[1][2] += a.y * b.z; acc[1][3] += a.y * b.w;
        acc[2][0] += a.z * b.x; acc[2][1] += a.z * b.y; acc[2][2] += a.z * b.z; acc[2][3] += a.z * b.w;
        acc[3][0] += a.w * b.x; acc[3][1] += a.w * b.y; acc[3][2] += a.w * b.z; acc[3][3] += a.w * b.w;
    }

    float4 bv = *(const float4*)&bias[col0 + cg * 4];
    #pragma unroll
    for (int i = 0; i < 4; ++i) {
        int r = row0 + rg * 4 + i;
        if (r < N_NODES) {
            float4 ov = make_float4(acc[i][0] + bv.x, acc[i][1] + bv.y,
                                    acc[i][2] + bv.z, acc[i][3] + bv.w);
            *(float4*)&out[(size_t)r * D + col0 + cg * 4] = ov;
        }
    }
}

extern "C" void kernel_launch(void* const* d_in, const int* in_sizes, int n_in,
                              void* d_out, int out_size, void* d_ws, size_t ws_size,
                              hipStream_t stream) {
    const float* node_emb = (const float*)d_in[0];
    const int*   edge     = (const int*)d_in[1];   // [2,E]: row 0 = src, row 1 = dst
    const float* weight   = (const float*)d_in[2]; // [D_OUT, D_IN] row-major
    const float* bias     = (const float*)d_in[3];
    float* out = (float*)d_out;

    char* ws = (char*)d_ws;
    float*        hbuf = (float*)ws;        ws += (size_t)N_NODES * D * sizeof(float);
    unsigned int* xb0  = (unsigned int*)ws; ws += (size_t)N_NODES * 64 * sizeof(unsigned int);
    unsigned int* xb1  = (unsigned int*)ws; ws += (size_t)N_NODES * 64 * sizeof(unsigned int);
    long long* csr  = (long long*)ws; ws += (size_t)N_EDGES * sizeof(long long);
    int*   rank     = (int*)ws;   ws += (size_t)N_EDGES * sizeof(int);
    int*   degR     = (int*)ws;   ws += (size_t)NREP * N_NODES * sizeof(int);  // -> pref
    int*   deg      = (int*)ws;   ws += (size_t)N_NODES * sizeof(int);
    int*   row_start= (int*)ws;   ws += (size_t)(N_NODES + 16) * sizeof(int);
    float* dinv     = (float*)ws; ws += (size_t)N_NODES * sizeof(float);
    float* selfw    = (float*)ws; ws += (size_t)N_NODES * sizeof(float);
    int*   part     = (int*)ws;   ws += 256 * sizeof(int);

    const int* srcp = edge;
    const int* dstp = edge + N_EDGES;

    hipMemsetAsync(degR, 0, (size_t)NREP * N_NODES * sizeof(int), stream);

    int deg_threads = N_EDGES / DEG_IPT;                       // 200000, exact
    deg_kernel<<<(deg_threads + 255) / 256, 256, 0, stream>>>(dstp, degR, rank, N_EDGES);
    combine_kernel<<<(N_NODES + 255) / 256, 256, 0, stream>>>(degR, deg, dinv, selfw, N_NODES);
    scan_part<<<N_SBLK, 256, 0, stream>>>(deg, part, N_NODES);
    scan_mid<<<1, 256, 0, stream>>>(part, N_SBLK);
    scan_fin<<<N_SBLK, 256, 0, stream>>>(deg, part, row_start, N_NODES);
    int sc_threads = N_EDGES / 4;                              // 400000, exact
    scatter_kernel<<<(sc_threads + 255) / 256, 256, 0, stream>>>(srcp, dstp, rank, row_start,
                                                                 degR, csr, dinv, N_EDGES);

    int n2 = N_NODES * D / 2;
    init_kernel<<<(n2 + 255) / 256, 256, 0, stream>>>((const float2*)node_emb, xb0,
                                                      (float2*)hbuf, n2);

    unsigned int* cur = xb0;
    unsigned int* nxt = xb1;
    for (int k = 0; k < K_HOPS; ++k) {
        agg_kernel<<<(N_NODES + 3) / 4, 256, 0, stream>>>(cur, nxt, (float2*)hbuf,
                                                          selfw, row_start, csr, k & 1);
        unsigned int* tmp = cur; cur = nxt; nxt = tmp;
    }

    // Out-of-place GEMM: reads hbuf (f32), writes d_out.
    dim3 ggrid((N_NODES + 63) / 64, 2);
    gemm_kernel<<<ggrid, 256, 0, stream>>>(hbuf, weight, bias, out);
}

// Round 10
// 1060.841 us; speedup vs baseline: 1.0064x; 1.0064x over previous
//
#include <hip/hip_runtime.h>

// SSGC: h = alpha*x0 + (1-alpha)/K * sum_{k=1..K} (D^-1/2 A_hat D^-1/2)^k x0 ; out = h W^T + b
// N=50000, E=1.6M, D=128, K=16, alpha=0.05.
// R17 = R14 champion (1060.7us) + GATHER_BLOCK(32) as the first step of the
//      stepped unroll. Model: agg is L3-latency-bound at ~25 outstanding misses/CU;
//      per-wave MLP was proven binding at 8->16 (R10/R12 vs R9: 2x). Avg degree 32
//      means one 32-wide flight-group covers most nodes' full edge list.
//      VGPR ~36 -> ~100 (still 5 waves/SIMD). Everything else untouched.
//      R16 lessons: deg nt-streams falsified (WRITE_SIZE unchanged -> atomic
//      write-through is unconditional; deg at ~67us floor); agg LDS-broadcast
//      neutral -> reverted to shfl.

#define N_NODES 50000
#define N_EDGES 1600000
#define D 128
#define K_HOPS 16
#define ALPHA 0.05f
#define HCOEF ((1.0f - ALPHA) / (float)K_HOPS)
#define NREP 8
#define N_SBLK ((N_NODES + 255) / 256)   // 196 scan blocks

// deg: 8 edges/thread -> replica of edge i is ((i >> 11) & 7) (2048 edges per block).
#define DEG_IPT 8
#define REP_OF(i) (((i) >> 11) & (NREP - 1))

__device__ __forceinline__ unsigned int f2bf(float f) {
    unsigned int u = __float_as_uint(f);
    return (u + 0x7FFFu + ((u >> 16) & 1u)) >> 16;   // RNE
}
__device__ __forceinline__ unsigned int pack_bf2(float x, float y) {
    return f2bf(x) | (f2bf(y) << 16);
}
__device__ __forceinline__ float bf_lo(unsigned int w) { return __uint_as_float(w << 16); }
__device__ __forceinline__ float bf_hi(unsigned int w) { return __uint_as_float(w & 0xFFFF0000u); }

// Replicated in-degree histogram, 8 edges per thread (two int4 loads).
__global__ void deg_kernel(const int* __restrict__ dst, int* __restrict__ degR,
                           int* __restrict__ rank, int e) {
    int gid = blockIdx.x * 256 + threadIdx.x;
    int i0 = gid * DEG_IPT;
    if (i0 >= e) return;
    int rep = REP_OF(i0);                    // all 8 edges share one replica
    int* base = degR + rep * N_NODES;
    int4 d0 = *(const int4*)&dst[i0];
    int4 d1 = *(const int4*)&dst[i0 + 4];
    int r[8];
    r[0] = atomicAdd(&base[d0.x], 1);
    r[1] = atomicAdd(&base[d0.y], 1);
    r[2] = atomicAdd(&base[d0.z], 1);
    r[3] = atomicAdd(&base[d0.w], 1);
    r[4] = atomicAdd(&base[d1.x], 1);
    r[5] = atomicAdd(&base[d1.y], 1);
    r[6] = atomicAdd(&base[d1.z], 1);
    r[7] = atomicAdd(&base[d1.w], 1);
    *(int4*)&rank[i0]     = make_int4(r[0], r[1], r[2], r[3]);
    *(int4*)&rank[i0 + 4] = make_int4(r[4], r[5], r[6], r[7]);
}

// Fold replicas: degR[r][i] becomes the exclusive prefix over replicas (pref),
// deg[i] = total. Also computes dinv/selfw.
__global__ void combine_kernel(int* __restrict__ degR, int* __restrict__ deg,
                               float* __restrict__ dinv, float* __restrict__ selfw, int n) {
    int i = blockIdx.x * 256 + threadIdx.x;
    if (i < n) {
        int run = 0;
        #pragma unroll
        for (int r = 0; r < NREP; ++r) {
            int v = degR[r * N_NODES + i];
            degR[r * N_NODES + i] = run;   // in-place: degR becomes pref
            run += v;
        }
        deg[i] = run;
        float di = rsqrtf((float)(run + 1));
        dinv[i] = di;
        selfw[i] = di * di;
    }
}

// 256-thread block exclusive scan (shfl wave scans + 4-wave LDS combine).
__device__ __forceinline__ int block_scan_excl(int v) {
    __shared__ int ws[4];
    int tid = threadIdx.x, lane = tid & 63, wid = tid >> 6;
    int s = v;
    #pragma unroll
    for (int off = 1; off < 64; off <<= 1) {
        int t = __shfl_up(s, off, 64);
        if (lane >= off) s += t;
    }
    if (lane == 63) ws[wid] = s;
    __syncthreads();
    int woff = 0;
    #pragma unroll
    for (int w = 0; w < 3; ++w)
        if (w < wid) woff += ws[w];
    return woff + s - v;
}

__global__ void scan_part(const int* __restrict__ deg, int* __restrict__ part, int n) {
    int i = blockIdx.x * 256 + threadIdx.x;
    int v = (i < n) ? deg[i] : 0;
    #pragma unroll
    for (int off = 1; off < 64; off <<= 1) v += __shfl_xor(v, off, 64);
    __shared__ int ws[4];
    if ((threadIdx.x & 63) == 0) ws[threadIdx.x >> 6] = v;
    __syncthreads();
    if (threadIdx.x == 0) part[blockIdx.x] = ws[0] + ws[1] + ws[2] + ws[3];
}

__global__ void scan_mid(int* __restrict__ part, int nb) {
    int tid = threadIdx.x;
    int v = (tid < nb) ? part[tid] : 0;
    int e = block_scan_excl(v);
    if (tid < nb) part[tid] = e;
}

__global__ void scan_fin(const int* __restrict__ deg, const int* __restrict__ part,
                         int* __restrict__ row_start, int n) {
    int i = blockIdx.x * 256 + threadIdx.x;
    int v = (i < n) ? deg[i] : 0;
    int e = block_scan_excl(v) + part[blockIdx.x];
    if (i < n) row_start[i] = e;
    if (i == n - 1) row_start[n] = e + v;
}

// One 8B scattered store per edge: record = (src, bitcast(norm weight)).
// 4 edges/thread for MLP on the random 4B gathers.
__global__ void scatter_kernel(const int* __restrict__ src, const int* __restrict__ dst,
                               const int* __restrict__ rank, const int* __restrict__ row_start,
                               const int* __restrict__ pref, int2* __restrict__ csr,
                               const float* __restrict__ dinv, int e) {
    int gid = blockIdx.x * 256 + threadIdx.x;
    int i0 = gid * 4;
    if (i0 >= e) return;
    int4 dv = *(const int4*)&dst[i0];
    int4 sv = *(const int4*)&src[i0];
    int4 rv = *(const int4*)&rank[i0];
    int d[4] = {dv.x, dv.y, dv.z, dv.w};
    int s[4] = {sv.x, sv.y, sv.z, sv.w};
    int r[4] = {rv.x, rv.y, rv.z, rv.w};
    int pos[4];
    float w[4];
    #pragma unroll
    for (int q = 0; q < 4; ++q) {
        int rep = REP_OF(i0 + q);
        pos[q] = row_start[d[q]] + pref[rep * N_NODES + d[q]] + r[q];
        w[q] = dinv[d[q]] * dinv[s[q]];
    }
    #pragma unroll
    for (int q = 0; q < 4; ++q)
        csr[pos[q]] = make_int2(s[q], __float_as_int(w[q]));
}

// x0 -> packed bf16 x; h = alpha * x0 (exact f32).
__global__ void init_kernel(const float2* __restrict__ x0, unsigned int* __restrict__ xb,
                            float2* __restrict__ h, int n2) {
    int i = blockIdx.x * blockDim.x + threadIdx.x;
    if (i < n2) {
        float2 v = x0[i];
        xb[i] = pack_bf2(v.x, v.y);
        h[i] = make_float2(ALPHA * v.x, ALPHA * v.y);
    }
}

// 32-bit offsets: xb spans 50000*64 dwords (12.8MB) -> fits a 32-bit voffset;
// avoids per-gather 64-bit address arithmetic.
#define GATHER_BLOCK(W)                                                         \
    {                                                                           \
        unsigned int g[W];                                                      \
        float wv[W];                                                            \
        _Pragma("unroll") for (int q = 0; q < W; ++q) {                         \
            int s = __shfl(rec.x, j + q);                                       \
            wv[q] = __int_as_float(__shfl(rec.y, j + q));                       \
            g[q] = xb[(unsigned int)s * 64u + (unsigned int)lane];              \
        }                                                                       \
        _Pragma("unroll") for (int q = 0; q < W; ++q) {                         \
            accx += wv[q] * bf_lo(g[q]);                                        \
            accy += wv[q] * bf_hi(g[q]);                                        \
        }                                                                       \
        j += W;                                                                 \
    }

// One wave (64 lanes) per node; lane owns features [2*lane, 2*lane+1] (one packed
// dword). Edge records loaded 64-at-a-time coalesced (nontemporal: streamed once,
// don't evict xb from L2), broadcast with shfl; stepped unroll 32/16/8/4 — the
// 32-wide step holds 32 gathers in flight per lane (avg degree 32 -> one flight
// group covers most nodes' full edge list).
// yb written nontemporal; h RMW (every 2nd hop) nontemporal both ways.
__global__ __launch_bounds__(256) void agg_kernel(
    const unsigned int* __restrict__ xb, unsigned int* __restrict__ yb,
    float2* __restrict__ h2, const float* __restrict__ selfw,
    const int* __restrict__ row_start, const int2* __restrict__ csr, int update_h) {
    int wid = threadIdx.x >> 6;
    int lane = threadIdx.x & 63;
    int node = blockIdx.x * 4 + wid;
    if (node >= N_NODES) return;

    int r0 = row_start[node];
    int r1 = row_start[node + 1];
    int deg = r1 - r0;
    unsigned int o = (unsigned int)node * 64u + (unsigned int)lane;

    unsigned int vw = xb[o];
    float sw = selfw[node];
    float accx = sw * bf_lo(vw), accy = sw * bf_hi(vw);

    for (int base = 0; base < deg; base += 64) {
        int cnt = deg - base;
        if (cnt > 64) cnt = 64;
        int idx = r0 + base + lane;
        if (idx >= r1) idx = r1 - 1;           // clamped lanes are never shfl-read
        long long rr = __builtin_nontemporal_load((const long long*)&csr[idx]);
        int2 rec;
        rec.x = (int)rr;                       // src
        rec.y = (int)(rr >> 32);               // bitcast(weight)

        int j = 0;
        while (j + 32 <= cnt) GATHER_BLOCK(32);
        if (j + 16 <= cnt) GATHER_BLOCK(16);
        if (j + 8 <= cnt) GATHER_BLOCK(8);
        if (j + 4 <= cnt) GATHER_BLOCK(4);
        for (; j < cnt; ++j) {
            int s = __shfl(rec.x, j);
            float w = __int_as_float(__shfl(rec.y, j));
            unsigned int gw = xb[(unsigned int)s * 64u + (unsigned int)lane];
            accx += w * bf_lo(gw);
            accy += w * bf_hi(gw);
        }
    }

    __builtin_nontemporal_store(pack_bf2(accx, accy), &yb[o]);   // bf16 next-hop state
    if (update_h) {
        union { long long ll; float2 f; } hu;
        hu.ll = __builtin_nontemporal_load((const long long*)&h2[o]);
        hu.f.x += HCOEF * (bf_lo(vw) + accx);  // x_k (rounded) + x_{k+1} (pre-round)
        hu.f.y += HCOEF * (bf_hi(vw) + accy);
        __builtin_nontemporal_store(hu.ll, (long long*)&h2[o]);
    }
}

// out[r][c] = sum_k h[r][k]*W[c][k] + bias[c]. h and out are DIFFERENT buffers.
// Block: 64 rows x 64 cols, 256 threads, 4x4 acc/thread. k-major LDS tiles.
__global__ __launch_bounds__(256) void gemm_kernel(
    const float* __restrict__ h, const float* __restrict__ w,
    const float* __restrict__ bias, float* __restrict__ out) {
    __shared__ float sAT[128][64];   // [k][row]
    __shared__ float sBT[128][64];   // [k][col]
    int tid = threadIdx.x;
    int row0 = blockIdx.x * 64;
    int col0 = blockIdx.y * 64;

    for (int idx = tid; idx < 64 * 32; idx += 256) {
        int r = idx & 63, kq = idx >> 6;
        float4 v;
        if (row0 + r < N_NODES)
            v = *(const float4*)&h[(size_t)(row0 + r) * D + kq * 4];
        else
            v = make_float4(0.f, 0.f, 0.f, 0.f);
        sAT[kq * 4 + 0][r] = v.x;
        sAT[kq * 4 + 1][r] = v.y;
        sAT[kq * 4 + 2][r] = v.z;
        sAT[kq * 4 + 3][r] = v.w;
    }
    for (int idx = tid; idx < 64 * 32; idx += 256) {
        int c = idx & 63, kq = idx >> 6;
        float4 v = *(const float4*)&w[(size_t)(col0 + c) * D + kq * 4];
        sBT[kq * 4 + 0][c] = v.x;
        sBT[kq * 4 + 1][c] = v.y;
        sBT[kq * 4 + 2][c] = v.z;
        sBT[kq * 4 + 3][c] = v.w;
    }
    __syncthreads();

    int cg = tid & 15;    // cols cg*4..+4
    int rg = tid >> 4;    // rows rg*4..+4
    float acc[4][4] = {};
    #pragma unroll 2
    for (int k = 0; k < 128; ++k) {
        float4 a = *(const float4*)&sAT[k][rg * 4];
        float4 b = *(const float4*)&sBT[k][cg * 4];
        acc[0][0] += a.x * b.x; acc[0][1] += a.x * b.y; acc[0][2] += a.x * b.z; acc[0][3] += a.x * b.w;
        acc[1][0] += a.y * b.x; acc[1][1] += a.y * b.y; acc[1][2] += a.y * b.z; acc[1][3] += a.y * b.w;
        acc[2][0] += a.z * b.x; acc[2][1] += a.z * b.y; acc[2][2] += a.z * b.z; acc[2][3] += a.z * b.w;
        acc[3][0] += a.w * b.x; acc[3][1] += a.w * b.y; acc[3][2] += a.w * b.z; acc[3][3] += a.w * b.w;
    }

    float4 bv = *(const float4*)&bias[col0 + cg * 4];
    #pragma unroll
    for (int i = 0; i < 4; ++i) {
        int r = row0 + rg * 4 + i;
        if (r < N_NODES) {
            float4 ov = make_float4(acc[i][0] + bv.x, acc[i][1] + bv.y,
                                    acc[i][2] + bv.z, acc[i][3] + bv.w);
            *(float4*)&out[(size_t)r * D + col0 + cg * 4] = ov;
        }
    }
}

extern "C" void kernel_launch(void* const* d_in, const int* in_sizes, int n_in,
                              void* d_out, int out_size, void* d_ws, size_t ws_size,
                              hipStream_t stream) {
    const float* node_emb = (const float*)d_in[0];
    const int*   edge     = (const int*)d_in[1];   // [2,E]: row 0 = src, row 1 = dst
    const float* weight   = (const float*)d_in[2]; // [D_OUT, D_IN] row-major
    const float* bias     = (const float*)d_in[3];
    float* out = (float*)d_out;

    char* ws = (char*)d_ws;
    float*        hbuf = (float*)ws;        ws += (size_t)N_NODES * D * sizeof(float);
    unsigned int* xb0  = (unsigned int*)ws; ws += (size_t)N_NODES * 64 * sizeof(unsigned int);
    unsigned int* xb1  = (unsigned int*)ws; ws += (size_t)N_NODES * 64 * sizeof(unsigned int);
    int2*  csr      = (int2*)ws;  ws += (size_t)N_EDGES * sizeof(int2);
    int*   rank     = (int*)ws;   ws += (size_t)N_EDGES * sizeof(int);
    int*   degR     = (int*)ws;   ws += (size_t)NREP * N_NODES * sizeof(int);  // -> pref
    int*   deg      = (int*)ws;   ws += (size_t)N_NODES * sizeof(int);
    int*   row_start= (int*)ws;   ws += (size_t)(N_NODES + 16) * sizeof(int);
    float* dinv     = (float*)ws; ws += (size_t)N_NODES * sizeof(float);
    float* selfw    = (float*)ws; ws += (size_t)N_NODES * sizeof(float);
    int*   part     = (int*)ws;   ws += 256 * sizeof(int);

    const int* srcp = edge;
    const int* dstp = edge + N_EDGES;

    hipMemsetAsync(degR, 0, (size_t)NREP * N_NODES * sizeof(int), stream);

    int deg_threads = N_EDGES / DEG_IPT;                       // 200000, exact
    deg_kernel<<<(deg_threads + 255) / 256, 256, 0, stream>>>(dstp, degR, rank, N_EDGES);
    combine_kernel<<<(N_NODES + 255) / 256, 256, 0, stream>>>(degR, deg, dinv, selfw, N_NODES);
    scan_part<<<N_SBLK, 256, 0, stream>>>(deg, part, N_NODES);
    scan_mid<<<1, 256, 0, stream>>>(part, N_SBLK);
    scan_fin<<<N_SBLK, 256, 0, stream>>>(deg, part, row_start, N_NODES);
    int sc_threads = N_EDGES / 4;                              // 400000, exact
    scatter_kernel<<<(sc_threads + 255) / 256, 256, 0, stream>>>(srcp, dstp, rank, row_start,
                                                                 degR, csr, dinv, N_EDGES);

    int n2 = N_NODES * D / 2;
    init_kernel<<<(n2 + 255) / 256, 256, 0, stream>>>((const float2*)node_emb, xb0,
                                                      (float2*)hbuf, n2);

    unsigned int* cur = xb0;
    unsigned int* nxt = xb1;
    for (int k = 0; k < K_HOPS; ++k) {
        agg_kernel<<<(N_NODES + 3) / 4, 256, 0, stream>>>(cur, nxt, (float2*)hbuf,
                                                          selfw, row_start, csr, k & 1);
        unsigned int* tmp = cur; cur = nxt; nxt = tmp;
    }

    // Out-of-place GEMM: reads hbuf (f32), writes d_out.
    dim3 ggrid((N_NODES + 63) / 64, 2);
    gemm_kernel<<<ggrid, 256, 0, stream>>>(hbuf, weight, bias, out);
}